// Round 1
// baseline (547.060 us; speedup 1.0000x reference)
//
#include <hip/hip_runtime.h>
#include <stdint.h>

// Problem: B=16, S=512, H=2048, NH=16, NKV=4, HD=128
// out = Wo-proj( softmax(rope(q) @ rope(k)^T * hd^-.5) @ v )  with GQA rep=4
//
// ws layout (f16 intermediates, total 138412032 bytes):
//   x_h   [8192,2048]        @ 0         (33.5MB)
//   w_h   [3072,2048]        @ 33554432  (Wq rows 0..2047, Wk 2048..2559, Wv 2560..3071)
//   wo_h  [2048,2048]        @ 46137344
//   q     [16,16,512,128]    @ 54525952
//   k     [16,4,512,128]     @ 88080384
//   vt    [16,4,128,512]     @ 96468992   (V transposed: d-major for PV B-operand)
//   attn  [8192,2048]        @ 104857600

typedef _Float16 f16;
typedef _Float16 f16x4 __attribute__((ext_vector_type(4)));
typedef _Float16 f16x8 __attribute__((ext_vector_type(8)));
typedef float f32x4 __attribute__((ext_vector_type(4)));

#define B_   16
#define S_   512
#define H_   2048
#define NH_  16
#define NKV_ 4
#define HD_  128
#define ATT_SCALE 0.08838834764831843f

#define AS1 __attribute__((address_space(1)))
#define AS3 __attribute__((address_space(3)))

// async global->LDS, 16B per lane. LDS dest = wave-uniform base + lane*16.
// generic->AS cast via uintptr_t: LDS generic ptr low 32 bits = LDS offset (aperture scheme).
__device__ __forceinline__ void async16(const void* g, const void* l) {
  __builtin_amdgcn_global_load_lds((const AS1 unsigned int*)(uintptr_t)g,
                                   (AS3 unsigned int*)(uintptr_t)l, 16, 0, 0);
}

// ---------------- fp32 -> f16 cast ----------------
__global__ __launch_bounds__(256) void cast_f32_f16(const float* __restrict__ src,
                                                    f16* __restrict__ dst, int n4) {
  int i = blockIdx.x * 256 + threadIdx.x;
  if (i < n4) {
    float4 v = reinterpret_cast<const float4*>(src)[i];
    f16x4 o = {(f16)v.x, (f16)v.y, (f16)v.z, (f16)v.w};
    reinterpret_cast<f16x4*>(dst)[i] = o;
  }
}

// ---------------- GEMM1: qkv = x @ Wqkv^T, scatter epilogue ----------------
// A [8192,2048] row-major, W [3072,2048] row-major (both K-contiguous).
__global__ __launch_bounds__(256) void gemm_qkv(const f16* __restrict__ A,
                                                const f16* __restrict__ W,
                                                f16* __restrict__ qo,
                                                f16* __restrict__ ko,
                                                f16* __restrict__ vto) {
  __shared__ __align__(16) f16 As[128 * 32];
  __shared__ __align__(16) f16 Bs[128 * 32];
  const int K = 2048;
  const int m0 = blockIdx.x * 128;
  const int n0 = blockIdx.y * 128;
  const int tid = threadIdx.x;
  const int wave = tid >> 6, lane = tid & 63;
  const int quad = lane >> 4, l15 = lane & 15;
  const int wm = wave >> 1, wn = wave & 1;
  const int c0 = wave * 128 + lane;   // chunk ids staged by this thread: c0, c0+64
  const int row0 = c0 >> 2, kc0 = c0 & 3;
  const int row1 = (c0 + 64) >> 2, kc1 = (c0 + 64) & 3;

  f32x4 acc[4][4] = {};

  for (int k0 = 0; k0 < K; k0 += 32) {
    async16(A + (size_t)(m0 + row0) * K + k0 + kc0 * 8, (const char*)As + (wave * 128) * 16);
    async16(A + (size_t)(m0 + row1) * K + k0 + kc1 * 8, (const char*)As + (wave * 128 + 64) * 16);
    async16(W + (size_t)(n0 + row0) * K + k0 + kc0 * 8, (const char*)Bs + (wave * 128) * 16);
    async16(W + (size_t)(n0 + row1) * K + k0 + kc1 * 8, (const char*)Bs + (wave * 128 + 64) * 16);
    __syncthreads();  // drains vmcnt -> staging visible
    f16x8 a[4], b[4];
#pragma unroll
    for (int mi = 0; mi < 4; ++mi)
      a[mi] = *reinterpret_cast<const f16x8*>(As + (wm * 64 + mi * 16 + l15) * 32 + quad * 8);
#pragma unroll
    for (int ni = 0; ni < 4; ++ni)
      b[ni] = *reinterpret_cast<const f16x8*>(Bs + (wn * 64 + ni * 16 + l15) * 32 + quad * 8);
#pragma unroll
    for (int mi = 0; mi < 4; ++mi)
#pragma unroll
      for (int ni = 0; ni < 4; ++ni)
        acc[mi][ni] = __builtin_amdgcn_mfma_f32_16x16x32_f16(a[mi], b[ni], acc[mi][ni], 0, 0, 0);
    __syncthreads();  // before next-tile overwrite
  }

  const int b_ = m0 >> 9;  // batch, uniform per block (128 | 512)
#pragma unroll
  for (int mi = 0; mi < 4; ++mi) {
#pragma unroll
    for (int ni = 0; ni < 4; ++ni) {
      const int ncol = n0 + wn * 64 + ni * 16 + l15;
#pragma unroll
      for (int r = 0; r < 4; ++r) {
        const int mrow = m0 + wm * 64 + mi * 16 + quad * 4 + r;
        const int s = mrow & 511;
        const f16 val = (f16)acc[mi][ni][r];
        if (ncol < 2048) {                      // Q: [b, h, s, d]
          const int h = ncol >> 7, d = ncol & 127;
          qo[(((size_t)b_ * NH_ + h) * S_ + s) * HD_ + d] = val;
        } else if (ncol < 2560) {               // K: [b, kh, s, d]
          const int h = (ncol - 2048) >> 7, d = ncol & 127;
          ko[(((size_t)b_ * NKV_ + h) * S_ + s) * HD_ + d] = val;
        } else {                                // V transposed: [b, kh, d, s]
          const int h = (ncol - 2560) >> 7, d = ncol & 127;
          vto[(((size_t)b_ * NKV_ + h) * HD_ + d) * S_ + s] = val;
        }
      }
    }
  }
}

// ---------------- RoPE in-place on q and k ----------------
__global__ __launch_bounds__(256) void rope_kernel(f16* __restrict__ q, f16* __restrict__ k) {
  const int NQ = B_ * NH_ * S_ * 64;   // 8388608 pair-slots for q
  const int NT = NQ + B_ * NKV_ * S_ * 64;
  int idx = blockIdx.x * 256 + threadIdx.x;
  if (idx >= NT) return;
  f16* p;
  int t;
  if (idx < NQ) { p = q; t = idx; } else { p = k; t = idx - NQ; }
  const int d = t & 63;
  const int s = (t >> 6) & 511;
  const size_t base = (size_t)(t >> 6) * HD_;
  // angle = s * 10000^(-d/64) ; log2(10000)/64 = 0.20762050593045952
  const float ang = (float)s * exp2f((float)d * -0.20762050593045952f);
  float sn, cs;
  __sincosf(ang, &sn, &cs);
  const float x1 = (float)p[base + d], x2 = (float)p[base + d + 64];
  p[base + d] = (f16)(x1 * cs - x2 * sn);
  p[base + d + 64] = (f16)(x2 * cs + x1 * sn);
}

// ---------------- flash attention ----------------
// grid (4 qtiles, 16 heads, 16 batch), 256 thr = 4 waves; wave handles 32 q-rows.
__global__ __launch_bounds__(256) void attn_kernel(const f16* __restrict__ q,
                                                   const f16* __restrict__ k,
                                                   const f16* __restrict__ vt,
                                                   f16* __restrict__ out) {
  __shared__ __align__(16) f16 Qs[128 * 128];      // [qrow][d]
  __shared__ __align__(16) f16 Ks[128 * 128];      // [key][d]
  __shared__ __align__(16) f16 Vs[128 * 128];      // [d][key]  (from vt)
  __shared__ __align__(16) f16 Ps[4][32 * 136];    // per-wave P, pad->conflict-free + 16B-aligned

  const int qt = blockIdx.x, h = blockIdx.y, b = blockIdx.z;
  const int kvh = h >> 2;
  const int tid = threadIdx.x;
  const int wave = tid >> 6, lane = tid & 63;
  const int quad = lane >> 4, l15 = lane & 15;
  const int sm0 = wave * 32;
  const int cw = wave * 512 + lane;  // staging chunk base

  const f16* qbase = q + (((size_t)b * NH_ + h) * S_ + qt * 128) * HD_;
  const f16* kbase = k + ((size_t)b * NKV_ + kvh) * S_ * HD_;
  const f16* vbase = vt + ((size_t)b * NKV_ + kvh) * HD_ * S_;

#pragma unroll
  for (int i = 0; i < 8; ++i) {  // Q tile: 2048 chunks of 16B
    const int c = cw + i * 64;
    async16(qbase + (size_t)(c >> 4) * HD_ + (c & 15) * 8, (const char*)Qs + (wave * 512 + i * 64) * 16);
  }

  f32x4 O[2][8] = {};
  float mrun[2][4], lrun[2][4];
#pragma unroll
  for (int mi = 0; mi < 2; ++mi)
#pragma unroll
    for (int r = 0; r < 4; ++r) { mrun[mi][r] = -3.0e38f; lrun[mi][r] = 0.f; }

  for (int j = 0; j < 4; ++j) {
    if (j) __syncthreads();  // all waves done with previous K/V tiles
#pragma unroll
    for (int i = 0; i < 8; ++i) {
      const int c = cw + i * 64;
      async16(kbase + (size_t)(j * 128 + (c >> 4)) * HD_ + (c & 15) * 8,
              (const char*)Ks + (wave * 512 + i * 64) * 16);
    }
#pragma unroll
    for (int i = 0; i < 8; ++i) {
      const int c = cw + i * 64;
      async16(vbase + (size_t)(c >> 4) * S_ + j * 128 + (c & 15) * 8,
              (const char*)Vs + (wave * 512 + i * 64) * 16);
    }
    __syncthreads();

    // S = Q @ K^T for this wave's 32-row strip
    f32x4 Sc[2][8] = {};
#pragma unroll
    for (int ks = 0; ks < 4; ++ks) {
      f16x8 aq[2], bk[8];
#pragma unroll
      for (int mi = 0; mi < 2; ++mi)
        aq[mi] = *reinterpret_cast<const f16x8*>(Qs + (sm0 + mi * 16 + l15) * 128 + ks * 32 + quad * 8);
#pragma unroll
      for (int ni = 0; ni < 8; ++ni)
        bk[ni] = *reinterpret_cast<const f16x8*>(Ks + (ni * 16 + l15) * 128 + ks * 32 + quad * 8);
#pragma unroll
      for (int mi = 0; mi < 2; ++mi)
#pragma unroll
        for (int ni = 0; ni < 8; ++ni)
          Sc[mi][ni] = __builtin_amdgcn_mfma_f32_16x16x32_f16(aq[mi], bk[ni], Sc[mi][ni], 0, 0, 0);
    }

    // online softmax (C-layout: row = quad*4+r on 16 lanes, col = ni*16+l15)
#pragma unroll
    for (int mi = 0; mi < 2; ++mi) {
#pragma unroll
      for (int r = 0; r < 4; ++r) {
        float mx = -3.0e38f;
#pragma unroll
        for (int ni = 0; ni < 8; ++ni) mx = fmaxf(mx, Sc[mi][ni][r]);
        mx *= ATT_SCALE;
#pragma unroll
        for (int off = 1; off < 16; off <<= 1) mx = fmaxf(mx, __shfl_xor(mx, off));
        const float mnew = fmaxf(mrun[mi][r], mx);
        const float alpha = __expf(mrun[mi][r] - mnew);
        float rs = 0.f;
#pragma unroll
        for (int ni = 0; ni < 8; ++ni) {
          const float pv = __expf(Sc[mi][ni][r] * ATT_SCALE - mnew);
          Sc[mi][ni][r] = pv;
          rs += pv;
        }
#pragma unroll
        for (int off = 1; off < 16; off <<= 1) rs += __shfl_xor(rs, off);
        lrun[mi][r] = lrun[mi][r] * alpha + rs;
        mrun[mi][r] = mnew;
#pragma unroll
        for (int ni = 0; ni < 8; ++ni) O[mi][ni][r] *= alpha;
#pragma unroll
        for (int ni = 0; ni < 8; ++ni)
          Ps[wave][(mi * 16 + quad * 4 + r) * 136 + ni * 16 + l15] = (f16)Sc[mi][ni][r];
      }
    }

    // O += P @ V  (P from per-wave LDS in A-layout; Vs rows are d, k-dim = key)
#pragma unroll
    for (int ks = 0; ks < 4; ++ks) {
      f16x8 ap[2], bv[8];
#pragma unroll
      for (int mi = 0; mi < 2; ++mi)
        ap[mi] = *reinterpret_cast<const f16x8*>(&Ps[wave][(mi * 16 + l15) * 136 + ks * 32 + quad * 8]);
#pragma unroll
      for (int ni = 0; ni < 8; ++ni)
        bv[ni] = *reinterpret_cast<const f16x8*>(Vs + (ni * 16 + l15) * 128 + ks * 32 + quad * 8);
#pragma unroll
      for (int mi = 0; mi < 2; ++mi)
#pragma unroll
        for (int ni = 0; ni < 8; ++ni)
          O[mi][ni] = __builtin_amdgcn_mfma_f32_16x16x32_f16(ap[mi], bv[ni], O[mi][ni], 0, 0, 0);
    }
  }

  // epilogue: normalize, write attn[b, s, h, d]
#pragma unroll
  for (int mi = 0; mi < 2; ++mi) {
#pragma unroll
    for (int r = 0; r < 4; ++r) {
      const float inv = 1.f / lrun[mi][r];
      const int srow = qt * 128 + sm0 + mi * 16 + quad * 4 + r;
#pragma unroll
      for (int ni = 0; ni < 8; ++ni)
        out[((size_t)b * S_ + srow) * H_ + h * HD_ + ni * 16 + l15] = (f16)(O[mi][ni][r] * inv);
    }
  }
}

// ---------------- GEMM2: out = attn @ Wo^T (fp32 out) ----------------
__global__ __launch_bounds__(256) void gemm_out(const f16* __restrict__ A,
                                                const f16* __restrict__ W,
                                                float* __restrict__ out) {
  __shared__ __align__(16) f16 As[128 * 32];
  __shared__ __align__(16) f16 Bs[128 * 32];
  const int K = 2048;
  const int m0 = blockIdx.x * 128;
  const int n0 = blockIdx.y * 128;
  const int tid = threadIdx.x;
  const int wave = tid >> 6, lane = tid & 63;
  const int quad = lane >> 4, l15 = lane & 15;
  const int wm = wave >> 1, wn = wave & 1;
  const int c0 = wave * 128 + lane;
  const int row0 = c0 >> 2, kc0 = c0 & 3;
  const int row1 = (c0 + 64) >> 2, kc1 = (c0 + 64) & 3;

  f32x4 acc[4][4] = {};

  for (int k0 = 0; k0 < K; k0 += 32) {
    async16(A + (size_t)(m0 + row0) * K + k0 + kc0 * 8, (const char*)As + (wave * 128) * 16);
    async16(A + (size_t)(m0 + row1) * K + k0 + kc1 * 8, (const char*)As + (wave * 128 + 64) * 16);
    async16(W + (size_t)(n0 + row0) * K + k0 + kc0 * 8, (const char*)Bs + (wave * 128) * 16);
    async16(W + (size_t)(n0 + row1) * K + k0 + kc1 * 8, (const char*)Bs + (wave * 128 + 64) * 16);
    __syncthreads();
    f16x8 a[4], b[4];
#pragma unroll
    for (int mi = 0; mi < 4; ++mi)
      a[mi] = *reinterpret_cast<const f16x8*>(As + (wm * 64 + mi * 16 + l15) * 32 + quad * 8);
#pragma unroll
    for (int ni = 0; ni < 4; ++ni)
      b[ni] = *reinterpret_cast<const f16x8*>(Bs + (wn * 64 + ni * 16 + l15) * 32 + quad * 8);
#pragma unroll
    for (int mi = 0; mi < 4; ++mi)
#pragma unroll
      for (int ni = 0; ni < 4; ++ni)
        acc[mi][ni] = __builtin_amdgcn_mfma_f32_16x16x32_f16(a[mi], b[ni], acc[mi][ni], 0, 0, 0);
    __syncthreads();
  }

#pragma unroll
  for (int mi = 0; mi < 4; ++mi) {
#pragma unroll
    for (int ni = 0; ni < 4; ++ni) {
      const int ncol = n0 + wn * 64 + ni * 16 + l15;
#pragma unroll
      for (int r = 0; r < 4; ++r) {
        const int mrow = m0 + wm * 64 + mi * 16 + quad * 4 + r;
        out[(size_t)mrow * 2048 + ncol] = acc[mi][ni][r];
      }
    }
  }
}

extern "C" void kernel_launch(void* const* d_in, const int* in_sizes, int n_in,
                              void* d_out, int out_size, void* d_ws, size_t ws_size,
                              hipStream_t stream) {
  const float* x = (const float*)d_in[0];
  const float* Wq = (const float*)d_in[1];
  const float* Wk = (const float*)d_in[2];
  const float* Wv = (const float*)d_in[3];
  const float* Wo = (const float*)d_in[4];
  float* out = (float*)d_out;
  char* ws = (char*)d_ws;

  f16* x_h  = (f16*)(ws + 0);
  f16* w_h  = (f16*)(ws + 33554432);
  f16* wo_h = (f16*)(ws + 46137344);
  f16* qb   = (f16*)(ws + 54525952);
  f16* kb   = (f16*)(ws + 88080384);
  f16* vtb  = (f16*)(ws + 96468992);
  f16* attn = (f16*)(ws + 104857600);  // needs ws_size >= 138412032

  cast_f32_f16<<<16384, 256, 0, stream>>>(x, x_h, 4194304);
  cast_f32_f16<<<4096, 256, 0, stream>>>(Wq, w_h, 1048576);
  cast_f32_f16<<<1024, 256, 0, stream>>>(Wk, w_h + 2048 * 2048, 262144);
  cast_f32_f16<<<1024, 256, 0, stream>>>(Wv, w_h + 2560 * 2048, 262144);
  cast_f32_f16<<<4096, 256, 0, stream>>>(Wo, wo_h, 1048576);

  gemm_qkv<<<dim3(64, 24), 256, 0, stream>>>(x_h, w_h, qb, kb, vtb);
  rope_kernel<<<40960, 256, 0, stream>>>(qb, kb);
  attn_kernel<<<dim3(4, 16, 16), 256, 0, stream>>>(qb, kb, vtb, attn);
  gemm_out<<<dim3(64, 16), 256, 0, stream>>>(attn, wo_h, out);
}

// Round 2
// 449.430 us; speedup vs baseline: 1.2172x; 1.2172x over previous
//
#include <hip/hip_runtime.h>
#include <stdint.h>

// Problem: B=16, S=512, H=2048, NH=16, NKV=4, HD=128
// out = Wo-proj( softmax(rope(q) @ rope(k)^T * hd^-.5) @ v )  with GQA rep=4
//
// ws layout (f16 intermediates):
//   x_h   [8192,2048]        @ 0
//   w_h   [3072,2048]        @ 33554432  (Wq 0..2047, Wk 2048..2559, Wv 2560..3071)
//   wo_h  [2048,2048]        @ 46137344
//   q     [16,16,512,128]    @ 54525952   (RoPE applied in gemm_qkv epilogue)
//   k     [16,4,512,128]     @ 88080384   (RoPE applied)
//   vt    [16,4,128,512]     @ 96468992   (V transposed)
//   attn  [8192,2048]        @ 104857600

typedef _Float16 f16;
typedef _Float16 f16x4 __attribute__((ext_vector_type(4)));
typedef _Float16 f16x8 __attribute__((ext_vector_type(8)));
typedef float f32x4 __attribute__((ext_vector_type(4)));

#define B_   16
#define S_   512
#define H_   2048
#define NH_  16
#define NKV_ 4
#define HD_  128
#define ATT_SCALE 0.08838834764831843f
#define LOG2_10000_DIV64 0.20762050593045952f

#define AS1 __attribute__((address_space(1)))
#define AS3 __attribute__((address_space(3)))

// async global->LDS, 16B/lane. LDS dest must be wave-uniform; HW adds lane*16.
__device__ __forceinline__ void async16(const void* g, const void* l) {
  __builtin_amdgcn_global_load_lds((const AS1 unsigned int*)(uintptr_t)g,
                                   (AS3 unsigned int*)(uintptr_t)l, 16, 0, 0);
}

// ---------------- fp32 -> f16 cast ----------------
__global__ __launch_bounds__(256) void cast_f32_f16(const float* __restrict__ src,
                                                    f16* __restrict__ dst, int n4) {
  int i = blockIdx.x * 256 + threadIdx.x;
  if (i < n4) {
    float4 v = reinterpret_cast<const float4*>(src)[i];
    f16x4 o = {(f16)v.x, (f16)v.y, (f16)v.z, (f16)v.w};
    reinterpret_cast<f16x4*>(dst)[i] = o;
  }
}

// ---------------- GEMM1: qkv = x @ Wqkv^T, fused RoPE + scatter epilogue ----
// Wave tiling: wave owns 32 rows x 128 cols, so each block's 128 cols = one
// head exactly and the RoPE pair (d, d+64) lives in the same lane (ni, ni+4).
__global__ __launch_bounds__(256) void gemm_qkv(const f16* __restrict__ A,
                                                const f16* __restrict__ W,
                                                f16* __restrict__ qo,
                                                f16* __restrict__ ko,
                                                f16* __restrict__ vto) {
  __shared__ __align__(16) f16 As[128 * 32];
  __shared__ __align__(16) f16 Bs[128 * 32];
  const int K = 2048;
  const int m0 = blockIdx.x * 128;
  const int n0 = blockIdx.y * 128;
  const int tid = threadIdx.x;
  const int wave = tid >> 6, lane = tid & 63;
  const int quad = lane >> 4, l15 = lane & 15;
  const int c0 = wave * 128 + lane;   // staging chunk ids: c0, c0+64
  const int row0 = c0 >> 2, kc0 = c0 & 3;
  const int row1 = (c0 + 64) >> 2, kc1 = (c0 + 64) & 3;

  f32x4 acc[2][8] = {};

  for (int k0 = 0; k0 < K; k0 += 32) {
    async16(A + (size_t)(m0 + row0) * K + k0 + kc0 * 8, (const char*)As + (wave * 128) * 16);
    async16(A + (size_t)(m0 + row1) * K + k0 + kc1 * 8, (const char*)As + (wave * 128 + 64) * 16);
    async16(W + (size_t)(n0 + row0) * K + k0 + kc0 * 8, (const char*)Bs + (wave * 128) * 16);
    async16(W + (size_t)(n0 + row1) * K + k0 + kc1 * 8, (const char*)Bs + (wave * 128 + 64) * 16);
    __syncthreads();
    f16x8 a[2], b[8];
#pragma unroll
    for (int mi = 0; mi < 2; ++mi)
      a[mi] = *reinterpret_cast<const f16x8*>(As + (wave * 32 + mi * 16 + l15) * 32 + quad * 8);
#pragma unroll
    for (int ni = 0; ni < 8; ++ni)
      b[ni] = *reinterpret_cast<const f16x8*>(Bs + (ni * 16 + l15) * 32 + quad * 8);
#pragma unroll
    for (int mi = 0; mi < 2; ++mi)
#pragma unroll
      for (int ni = 0; ni < 8; ++ni)
        acc[mi][ni] = __builtin_amdgcn_mfma_f32_16x16x32_f16(a[mi], b[ni], acc[mi][ni], 0, 0, 0);
    __syncthreads();
  }

  const int b_ = m0 >> 9;  // batch (uniform per block)
  if (n0 >= 2560) {
    // ---- V: no rope, store transposed [b, kh, d, s] ----
    const int h = (n0 - 2560) >> 7;
    f16* vb = vto + ((size_t)b_ * NKV_ + h) * HD_ * S_;
#pragma unroll
    for (int mi = 0; mi < 2; ++mi)
#pragma unroll
      for (int r = 0; r < 4; ++r) {
        const int s = (m0 + wave * 32 + mi * 16 + quad * 4 + r) & 511;
#pragma unroll
        for (int ni = 0; ni < 8; ++ni) {
          const int d = ni * 16 + l15;
          vb[(size_t)d * S_ + s] = (f16)acc[mi][ni][r];
        }
      }
  } else {
    // ---- Q or K: fused RoPE, store [b, h, s, d] ----
    f16* ob = (n0 < 2048) ? (qo + ((size_t)b_ * NH_ + (n0 >> 7)) * S_ * HD_)
                          : (ko + ((size_t)b_ * NKV_ + ((n0 - 2048) >> 7)) * S_ * HD_);
    float invf[4];
#pragma unroll
    for (int ni = 0; ni < 4; ++ni)
      invf[ni] = exp2f((float)(ni * 16 + l15) * -LOG2_10000_DIV64);
#pragma unroll
    for (int mi = 0; mi < 2; ++mi)
#pragma unroll
      for (int r = 0; r < 4; ++r) {
        const int s = (m0 + wave * 32 + mi * 16 + quad * 4 + r) & 511;
        const size_t rb = (size_t)s * HD_;
#pragma unroll
        for (int ni = 0; ni < 4; ++ni) {
          const int d = ni * 16 + l15;  // 0..63
          float sn, cs;
          __sincosf((float)s * invf[ni], &sn, &cs);
          const float x1 = acc[mi][ni][r], x2 = acc[mi][ni + 4][r];
          ob[rb + d] = (f16)(x1 * cs - x2 * sn);
          ob[rb + d + 64] = (f16)(x2 * cs + x1 * sn);
        }
      }
  }
}

// ---------------- flash attention ----------------
// 512 thr = 8 waves; wave owns 16 q-rows. Q/K/V tiles XOR-swizzled in LDS:
// row r's 16B-chunk c stored at slot c^(r&15) -> frag reads spread l15 lanes
// over all 16 slots (<=2-way bank aliasing, free) instead of 16-way conflicts.
__global__ __launch_bounds__(512) void attn_kernel(const f16* __restrict__ q,
                                                   const f16* __restrict__ k,
                                                   const f16* __restrict__ vt,
                                                   f16* __restrict__ out) {
  __shared__ __align__(16) f16 Qs[128 * 128];
  __shared__ __align__(16) f16 Ks[128 * 128];
  __shared__ __align__(16) f16 Vs[128 * 128];   // [d][key]
  __shared__ __align__(16) f16 Ps[8][16 * 136];

  const int qt = blockIdx.x, h = blockIdx.y, b = blockIdx.z;
  const int kvh = h >> 2;
  const int tid = threadIdx.x;
  const int wave = tid >> 6, lane = tid & 63;
  const int quad = lane >> 4, l15 = lane & 15;
  const int sm0 = wave * 16;

  const f16* qbase = q + (((size_t)b * NH_ + h) * S_ + qt * 128) * HD_;
  const f16* kbase = k + ((size_t)b * NKV_ + kvh) * S_ * HD_;
  const f16* vbase = vt + ((size_t)b * NKV_ + kvh) * HD_ * S_;

  // stage Q tile, swizzled: LDS chunk L holds global chunk (r, (L&15)^(r&15))
#pragma unroll
  for (int i = 0; i < 4; ++i) {
    const int L = wave * 256 + i * 64 + lane;
    const int r = L >> 4;
    const int c = (L & 15) ^ (r & 15);
    async16(qbase + (size_t)r * HD_ + c * 8, (const char*)Qs + (size_t)(wave * 256 + i * 64) * 16);
  }

  f32x4 O[8] = {};
  float mrun[4], lrun[4];
#pragma unroll
  for (int r = 0; r < 4; ++r) { mrun[r] = -3.0e38f; lrun[r] = 0.f; }

  for (int j = 0; j < 4; ++j) {
    if (j) __syncthreads();  // waves done reading previous K/V tiles
#pragma unroll
    for (int i = 0; i < 4; ++i) {
      const int L = wave * 256 + i * 64 + lane;
      const int r = L >> 4;
      const int c = (L & 15) ^ (r & 15);
      async16(kbase + (size_t)(j * 128 + r) * HD_ + c * 8,
              (const char*)Ks + (size_t)(wave * 256 + i * 64) * 16);
      async16(vbase + (size_t)r * S_ + j * 128 + c * 8,
              (const char*)Vs + (size_t)(wave * 256 + i * 64) * 16);
    }
    __syncthreads();  // drains vmcnt -> tiles visible

    // S = Q @ K^T (16 q-rows per wave x 128 keys)
    f32x4 Sc[8] = {};
#pragma unroll
    for (int ks = 0; ks < 4; ++ks) {
      f16x8 aq, bk[8];
      aq = *reinterpret_cast<const f16x8*>(Qs + ((sm0 + l15) * 16 + (((ks * 4 + quad) ^ l15))) * 8);
#pragma unroll
      for (int ni = 0; ni < 8; ++ni)
        bk[ni] = *reinterpret_cast<const f16x8*>(Ks + ((ni * 16 + l15) * 16 + ((ks * 4 + quad) ^ l15)) * 8);
#pragma unroll
      for (int ni = 0; ni < 8; ++ni)
        Sc[ni] = __builtin_amdgcn_mfma_f32_16x16x32_f16(aq, bk[ni], Sc[ni], 0, 0, 0);
    }

    // online softmax (C-layout: row=quad*4+r, col=ni*16+l15)
#pragma unroll
    for (int r = 0; r < 4; ++r) {
      float mx = -3.0e38f;
#pragma unroll
      for (int ni = 0; ni < 8; ++ni) mx = fmaxf(mx, Sc[ni][r]);
      mx *= ATT_SCALE;
#pragma unroll
      for (int off = 1; off < 16; off <<= 1) mx = fmaxf(mx, __shfl_xor(mx, off));
      const float mnew = fmaxf(mrun[r], mx);
      const float alpha = __expf(mrun[r] - mnew);
      float rs = 0.f;
#pragma unroll
      for (int ni = 0; ni < 8; ++ni) {
        const float pv = __expf(Sc[ni][r] * ATT_SCALE - mnew);
        Sc[ni][r] = pv;
        rs += pv;
      }
#pragma unroll
      for (int off = 1; off < 16; off <<= 1) rs += __shfl_xor(rs, off);
      lrun[r] = lrun[r] * alpha + rs;
      mrun[r] = mnew;
#pragma unroll
      for (int ni = 0; ni < 8; ++ni) O[ni][r] *= alpha;
#pragma unroll
      for (int ni = 0; ni < 8; ++ni)
        Ps[wave][(quad * 4 + r) * 136 + ni * 16 + l15] = (f16)Sc[ni][r];
    }

    // O += P @ V (per-wave P, no barrier needed; Vs rows are d, k-dim = key)
#pragma unroll
    for (int ks = 0; ks < 4; ++ks) {
      f16x8 ap, bv[8];
      ap = *reinterpret_cast<const f16x8*>(&Ps[wave][l15 * 136 + ks * 32 + quad * 8]);
#pragma unroll
      for (int ni = 0; ni < 8; ++ni)
        bv[ni] = *reinterpret_cast<const f16x8*>(Vs + ((ni * 16 + l15) * 16 + ((ks * 4 + quad) ^ l15)) * 8);
#pragma unroll
      for (int ni = 0; ni < 8; ++ni)
        O[ni] = __builtin_amdgcn_mfma_f32_16x16x32_f16(ap, bv[ni], O[ni], 0, 0, 0);
    }
  }

  // epilogue: normalize, write attn[b, s, h*128 + d]
#pragma unroll
  for (int r = 0; r < 4; ++r) {
    const float inv = 1.f / lrun[r];
    const int srow = qt * 128 + sm0 + quad * 4 + r;
#pragma unroll
    for (int ni = 0; ni < 8; ++ni)
      out[((size_t)b * S_ + srow) * H_ + h * HD_ + ni * 16 + l15] = (f16)(O[ni][r] * inv);
  }
}

// ---------------- GEMM2: out = attn @ Wo^T (fp32 out) ----------------
__global__ __launch_bounds__(256) void gemm_out(const f16* __restrict__ A,
                                                const f16* __restrict__ W,
                                                float* __restrict__ out) {
  __shared__ __align__(16) f16 As[128 * 32];
  __shared__ __align__(16) f16 Bs[128 * 32];
  const int K = 2048;
  const int m0 = blockIdx.x * 128;
  const int n0 = blockIdx.y * 128;
  const int tid = threadIdx.x;
  const int wave = tid >> 6, lane = tid & 63;
  const int quad = lane >> 4, l15 = lane & 15;
  const int wm = wave >> 1, wn = wave & 1;
  const int c0 = wave * 128 + lane;
  const int row0 = c0 >> 2, kc0 = c0 & 3;
  const int row1 = (c0 + 64) >> 2, kc1 = (c0 + 64) & 3;

  f32x4 acc[4][4] = {};

  for (int k0 = 0; k0 < K; k0 += 32) {
    async16(A + (size_t)(m0 + row0) * K + k0 + kc0 * 8, (const char*)As + (wave * 128) * 16);
    async16(A + (size_t)(m0 + row1) * K + k0 + kc1 * 8, (const char*)As + (wave * 128 + 64) * 16);
    async16(W + (size_t)(n0 + row0) * K + k0 + kc0 * 8, (const char*)Bs + (wave * 128) * 16);
    async16(W + (size_t)(n0 + row1) * K + k0 + kc1 * 8, (const char*)Bs + (wave * 128 + 64) * 16);
    __syncthreads();
    f16x8 a[4], b[4];
#pragma unroll
    for (int mi = 0; mi < 4; ++mi)
      a[mi] = *reinterpret_cast<const f16x8*>(As + (wm * 64 + mi * 16 + l15) * 32 + quad * 8);
#pragma unroll
    for (int ni = 0; ni < 4; ++ni)
      b[ni] = *reinterpret_cast<const f16x8*>(Bs + (wn * 64 + ni * 16 + l15) * 32 + quad * 8);
#pragma unroll
    for (int mi = 0; mi < 4; ++mi)
#pragma unroll
      for (int ni = 0; ni < 4; ++ni)
        acc[mi][ni] = __builtin_amdgcn_mfma_f32_16x16x32_f16(a[mi], b[ni], acc[mi][ni], 0, 0, 0);
    __syncthreads();
  }

#pragma unroll
  for (int mi = 0; mi < 4; ++mi) {
#pragma unroll
    for (int ni = 0; ni < 4; ++ni) {
      const int ncol = n0 + wn * 64 + ni * 16 + l15;
#pragma unroll
      for (int r = 0; r < 4; ++r) {
        const int mrow = m0 + wm * 64 + mi * 16 + quad * 4 + r;
        out[(size_t)mrow * 2048 + ncol] = acc[mi][ni][r];
      }
    }
  }
}

extern "C" void kernel_launch(void* const* d_in, const int* in_sizes, int n_in,
                              void* d_out, int out_size, void* d_ws, size_t ws_size,
                              hipStream_t stream) {
  const float* x = (const float*)d_in[0];
  const float* Wq = (const float*)d_in[1];
  const float* Wk = (const float*)d_in[2];
  const float* Wv = (const float*)d_in[3];
  const float* Wo = (const float*)d_in[4];
  float* out = (float*)d_out;
  char* ws = (char*)d_ws;

  f16* x_h  = (f16*)(ws + 0);
  f16* w_h  = (f16*)(ws + 33554432);
  f16* wo_h = (f16*)(ws + 46137344);
  f16* qb   = (f16*)(ws + 54525952);
  f16* kb   = (f16*)(ws + 88080384);
  f16* vtb  = (f16*)(ws + 96468992);
  f16* attn = (f16*)(ws + 104857600);  // needs ws_size >= 138412032

  cast_f32_f16<<<16384, 256, 0, stream>>>(x, x_h, 4194304);
  cast_f32_f16<<<4096, 256, 0, stream>>>(Wq, w_h, 1048576);
  cast_f32_f16<<<1024, 256, 0, stream>>>(Wk, w_h + 2048 * 2048, 262144);
  cast_f32_f16<<<1024, 256, 0, stream>>>(Wv, w_h + 2560 * 2048, 262144);
  cast_f32_f16<<<4096, 256, 0, stream>>>(Wo, wo_h, 1048576);

  gemm_qkv<<<dim3(64, 24), 256, 0, stream>>>(x_h, w_h, qb, kb, vtb);
  attn_kernel<<<dim3(4, 16, 16), 512, 0, stream>>>(qb, kb, vtb, attn);
  gemm_out<<<dim3(64, 16), 256, 0, stream>>>(attn, wo_h, out);
}

// Round 3
// 444.379 us; speedup vs baseline: 1.2311x; 1.0114x over previous
//
#include <hip/hip_runtime.h>
#include <stdint.h>

// Problem: B=16, S=512, H=2048, NH=16, NKV=4, HD=128
// out = Wo-proj( softmax(rope(q) @ rope(k)^T * hd^-.5) @ v )  with GQA rep=4
//
// ws layout (f16 intermediates):
//   x_h   [8192,2048]        @ 0
//   w_h   [3072,2048]        @ 33554432  (Wq 0..2047, Wk 2048..2559, Wv 2560..3071)
//   wo_h  [2048,2048]        @ 46137344
//   q     [16,16,512,128]    @ 54525952   (RoPE fused in gemm_qkv epilogue)
//   k     [16,4,512,128]     @ 88080384   (RoPE fused)
//   vt    [16,4,128,512]     @ 96468992   (V transposed)
//   attn  [8192,2048]        @ 104857600

typedef _Float16 f16;
typedef _Float16 f16x4 __attribute__((ext_vector_type(4)));
typedef _Float16 f16x8 __attribute__((ext_vector_type(8)));
typedef float f32x4 __attribute__((ext_vector_type(4)));

#define B_   16
#define S_   512
#define H_   2048
#define NH_  16
#define NKV_ 4
#define HD_  128
#define ATT_SCALE 0.08838834764831843f
#define LOG2_10000_DIV64 0.20762050593045952f

#define AS1 __attribute__((address_space(1)))
#define AS3 __attribute__((address_space(3)))

// async global->LDS, 16B/lane. LDS dest must be wave-uniform; HW adds lane*16.
__device__ __forceinline__ void async16(const void* g, const void* l) {
  __builtin_amdgcn_global_load_lds((const AS1 unsigned int*)(uintptr_t)g,
                                   (AS3 unsigned int*)(uintptr_t)l, 16, 0, 0);
}

// ---------------- fused fp32 -> f16 cast for all 5 inputs ----------------
// region boundaries are multiples of 256 -> branch is block-uniform.
__global__ __launch_bounds__(256) void cast_all(const float* __restrict__ x,
                                                const float* __restrict__ wq,
                                                const float* __restrict__ wk,
                                                const float* __restrict__ wv,
                                                const float* __restrict__ wo,
                                                f16* __restrict__ x_h,
                                                f16* __restrict__ w_h,
                                                f16* __restrict__ wo_h) {
  const int i = blockIdx.x * 256 + threadIdx.x;
  const float4* src;
  f16x4* dst;
  if (i < 4194304) {                 // x: 8192*2048
    src = (const float4*)x + i;            dst = (f16x4*)x_h + i;
  } else if (i < 5242880) {          // Wq: 2048*2048
    int j = i - 4194304;
    src = (const float4*)wq + j;           dst = (f16x4*)w_h + j;
  } else if (i < 5505024) {          // Wk: 512*2048
    int j = i - 5242880;
    src = (const float4*)wk + j;           dst = (f16x4*)w_h + 1048576 + j;
  } else if (i < 5767168) {          // Wv: 512*2048
    int j = i - 5505024;
    src = (const float4*)wv + j;           dst = (f16x4*)w_h + 1310720 + j;
  } else {                           // Wo: 2048*2048
    int j = i - 5767168;
    src = (const float4*)wo + j;           dst = (f16x4*)wo_h + j;
  }
  float4 v = *src;
  f16x4 o = {(f16)v.x, (f16)v.y, (f16)v.z, (f16)v.w};
  *dst = o;
}

// LDS chunk swizzle for 64B-row tiles (4x 16B chunks per row):
// chunk (r,c) stored at slot c ^ ((r>>1)&3). Frag reads then hit each
// bank-granule with only 2 lanes (free); staging stays lds-linear.
__device__ __forceinline__ int swz(int r, int c) { return c ^ ((r >> 1) & 3); }

// ---------------- GEMM1: qkv = x @ Wqkv^T, fused RoPE + scatter epilogue ----
// Wave tile 64 rows x 64 cols, cols split as {wn*32..+31} u {64+wn*32..+31}
// so the RoPE pair (d, d+64) is acc[mi][ni] / acc[mi][ni+2] in the same lane.
__global__ __launch_bounds__(256) void gemm_qkv(const f16* __restrict__ A,
                                                const f16* __restrict__ W,
                                                f16* __restrict__ qo,
                                                f16* __restrict__ ko,
                                                f16* __restrict__ vto) {
  __shared__ __align__(16) f16 As[128 * 32];
  __shared__ __align__(16) f16 Bs[128 * 32];
  const int K = 2048;
  const int m0 = blockIdx.x * 128;
  const int n0 = blockIdx.y * 128;
  const int tid = threadIdx.x;
  const int wave = tid >> 6, lane = tid & 63;
  const int quad = lane >> 4, l15 = lane & 15;
  const int wm = wave >> 1, wn = wave & 1;
  // staging: thread covers LDS granules G0=wave*128+lane and G0+64
  const int G0 = wave * 128 + lane;
  const int r0 = G0 >> 2, c0g = swz(r0, G0 & 3);            // swz is involutive
  const int r1 = (G0 + 64) >> 2, c1g = swz(r1, (G0 + 64) & 3);

  f32x4 acc[4][4] = {};

  for (int k0 = 0; k0 < K; k0 += 32) {
    async16(A + (size_t)(m0 + r0) * K + k0 + c0g * 8, (const char*)As + (size_t)G0 * 16);
    async16(A + (size_t)(m0 + r1) * K + k0 + c1g * 8, (const char*)As + (size_t)(G0 + 64) * 16);
    async16(W + (size_t)(n0 + r0) * K + k0 + c0g * 8, (const char*)Bs + (size_t)G0 * 16);
    async16(W + (size_t)(n0 + r1) * K + k0 + c1g * 8, (const char*)Bs + (size_t)(G0 + 64) * 16);
    __syncthreads();  // drains vmcnt -> staging visible
    f16x8 a[4], b[4];
#pragma unroll
    for (int mi = 0; mi < 4; ++mi) {
      const int row = wm * 64 + mi * 16 + l15;
      a[mi] = *reinterpret_cast<const f16x8*>(As + row * 32 + swz(row, quad) * 8);
    }
#pragma unroll
    for (int ni = 0; ni < 4; ++ni) {
      const int col = (ni >> 1) * 64 + wn * 32 + (ni & 1) * 16 + l15;
      b[ni] = *reinterpret_cast<const f16x8*>(Bs + col * 32 + swz(col, quad) * 8);
    }
#pragma unroll
    for (int mi = 0; mi < 4; ++mi)
#pragma unroll
      for (int ni = 0; ni < 4; ++ni)
        acc[mi][ni] = __builtin_amdgcn_mfma_f32_16x16x32_f16(a[mi], b[ni], acc[mi][ni], 0, 0, 0);
    __syncthreads();  // before next-tile overwrite
  }

  const int b_ = m0 >> 9;  // batch (uniform per block)
  if (n0 >= 2560) {
    // ---- V: no rope, store transposed [b, kh, d, s] ----
    const int h = (n0 - 2560) >> 7;
    f16* vb = vto + ((size_t)b_ * NKV_ + h) * HD_ * S_;
#pragma unroll
    for (int mi = 0; mi < 4; ++mi)
#pragma unroll
      for (int r = 0; r < 4; ++r) {
        const int s = (m0 + wm * 64 + mi * 16 + quad * 4 + r) & 511;
#pragma unroll
        for (int ni = 0; ni < 4; ++ni) {
          const int d = (ni >> 1) * 64 + wn * 32 + (ni & 1) * 16 + l15;
          vb[(size_t)d * S_ + s] = (f16)acc[mi][ni][r];
        }
      }
  } else {
    // ---- Q or K: fused RoPE, store [b, h, s, d] ----
    f16* ob = (n0 < 2048) ? (qo + ((size_t)b_ * NH_ + (n0 >> 7)) * S_ * HD_)
                          : (ko + ((size_t)b_ * NKV_ + ((n0 - 2048) >> 7)) * S_ * HD_);
    float invf[2];
#pragma unroll
    for (int ni = 0; ni < 2; ++ni)
      invf[ni] = exp2f((float)(wn * 32 + ni * 16 + l15) * -LOG2_10000_DIV64);
#pragma unroll
    for (int mi = 0; mi < 4; ++mi)
#pragma unroll
      for (int r = 0; r < 4; ++r) {
        const int s = (m0 + wm * 64 + mi * 16 + quad * 4 + r) & 511;
        const size_t rb = (size_t)s * HD_;
#pragma unroll
        for (int ni = 0; ni < 2; ++ni) {
          const int d = wn * 32 + ni * 16 + l15;  // 0..63
          float sn, cs;
          __sincosf((float)s * invf[ni], &sn, &cs);
          const float x1 = acc[mi][ni][r], x2 = acc[mi][ni + 2][r];
          ob[rb + d] = (f16)(x1 * cs - x2 * sn);
          ob[rb + d + 64] = (f16)(x2 * cs + x1 * sn);
        }
      }
  }
}

// ---------------- flash attention ----------------
// 512 thr = 8 waves; wave owns 16 q-rows. Q/K/V tiles XOR-swizzled in LDS
// (256B rows, chunk c at slot c^(r&15)) -> <=2-way bank aliasing (free).
__global__ __launch_bounds__(512) void attn_kernel(const f16* __restrict__ q,
                                                   const f16* __restrict__ k,
                                                   const f16* __restrict__ vt,
                                                   f16* __restrict__ out) {
  __shared__ __align__(16) f16 Qs[128 * 128];
  __shared__ __align__(16) f16 Ks[128 * 128];
  __shared__ __align__(16) f16 Vs[128 * 128];   // [d][key]
  __shared__ __align__(16) f16 Ps[8][16 * 136];

  const int qt = blockIdx.x, h = blockIdx.y, b = blockIdx.z;
  const int kvh = h >> 2;
  const int tid = threadIdx.x;
  const int wave = tid >> 6, lane = tid & 63;
  const int quad = lane >> 4, l15 = lane & 15;
  const int sm0 = wave * 16;

  const f16* qbase = q + (((size_t)b * NH_ + h) * S_ + qt * 128) * HD_;
  const f16* kbase = k + ((size_t)b * NKV_ + kvh) * S_ * HD_;
  const f16* vbase = vt + ((size_t)b * NKV_ + kvh) * HD_ * S_;

  // stage Q tile, swizzled: LDS chunk L holds global chunk (r, (L&15)^(r&15))
#pragma unroll
  for (int i = 0; i < 4; ++i) {
    const int L = wave * 256 + i * 64 + lane;
    const int r = L >> 4;
    const int c = (L & 15) ^ (r & 15);
    async16(qbase + (size_t)r * HD_ + c * 8, (const char*)Qs + (size_t)(wave * 256 + i * 64) * 16);
  }

  f32x4 O[8] = {};
  float mrun[4], lrun[4];
#pragma unroll
  for (int r = 0; r < 4; ++r) { mrun[r] = -3.0e38f; lrun[r] = 0.f; }

  for (int j = 0; j < 4; ++j) {
    if (j) __syncthreads();  // waves done reading previous K/V tiles
#pragma unroll
    for (int i = 0; i < 4; ++i) {
      const int L = wave * 256 + i * 64 + lane;
      const int r = L >> 4;
      const int c = (L & 15) ^ (r & 15);
      async16(kbase + (size_t)(j * 128 + r) * HD_ + c * 8,
              (const char*)Ks + (size_t)(wave * 256 + i * 64) * 16);
      async16(vbase + (size_t)r * S_ + j * 128 + c * 8,
              (const char*)Vs + (size_t)(wave * 256 + i * 64) * 16);
    }
    __syncthreads();  // drains vmcnt -> tiles visible

    // S = Q @ K^T (16 q-rows per wave x 128 keys)
    f32x4 Sc[8] = {};
#pragma unroll
    for (int ks = 0; ks < 4; ++ks) {
      f16x8 aq, bk[8];
      aq = *reinterpret_cast<const f16x8*>(Qs + ((sm0 + l15) * 16 + (((ks * 4 + quad) ^ l15))) * 8);
#pragma unroll
      for (int ni = 0; ni < 8; ++ni)
        bk[ni] = *reinterpret_cast<const f16x8*>(Ks + ((ni * 16 + l15) * 16 + ((ks * 4 + quad) ^ l15)) * 8);
#pragma unroll
      for (int ni = 0; ni < 8; ++ni)
        Sc[ni] = __builtin_amdgcn_mfma_f32_16x16x32_f16(aq, bk[ni], Sc[ni], 0, 0, 0);
    }

    // online softmax (C-layout: row=quad*4+r, col=ni*16+l15)
#pragma unroll
    for (int r = 0; r < 4; ++r) {
      float mx = -3.0e38f;
#pragma unroll
      for (int ni = 0; ni < 8; ++ni) mx = fmaxf(mx, Sc[ni][r]);
      mx *= ATT_SCALE;
#pragma unroll
      for (int off = 1; off < 16; off <<= 1) mx = fmaxf(mx, __shfl_xor(mx, off));
      const float mnew = fmaxf(mrun[r], mx);
      const float alpha = __expf(mrun[r] - mnew);
      float rs = 0.f;
#pragma unroll
      for (int ni = 0; ni < 8; ++ni) {
        const float pv = __expf(Sc[ni][r] * ATT_SCALE - mnew);
        Sc[ni][r] = pv;
        rs += pv;
      }
#pragma unroll
      for (int off = 1; off < 16; off <<= 1) rs += __shfl_xor(rs, off);
      lrun[r] = lrun[r] * alpha + rs;
      mrun[r] = mnew;
#pragma unroll
      for (int ni = 0; ni < 8; ++ni) O[ni][r] *= alpha;
#pragma unroll
      for (int ni = 0; ni < 8; ++ni)
        Ps[wave][(quad * 4 + r) * 136 + ni * 16 + l15] = (f16)Sc[ni][r];
    }

    // O += P @ V (per-wave P, no barrier needed; Vs rows are d, k-dim = key)
#pragma unroll
    for (int ks = 0; ks < 4; ++ks) {
      f16x8 ap, bv[8];
      ap = *reinterpret_cast<const f16x8*>(&Ps[wave][l15 * 136 + ks * 32 + quad * 8]);
#pragma unroll
      for (int ni = 0; ni < 8; ++ni)
        bv[ni] = *reinterpret_cast<const f16x8*>(Vs + ((ni * 16 + l15) * 16 + ((ks * 4 + quad) ^ l15)) * 8);
#pragma unroll
      for (int ni = 0; ni < 8; ++ni)
        O[ni] = __builtin_amdgcn_mfma_f32_16x16x32_f16(ap, bv[ni], O[ni], 0, 0, 0);
    }
  }

  // epilogue: normalize, write attn[b, s, h*128 + d]
#pragma unroll
  for (int r = 0; r < 4; ++r) {
    const float inv = 1.f / lrun[r];
    const int srow = qt * 128 + sm0 + quad * 4 + r;
#pragma unroll
    for (int ni = 0; ni < 8; ++ni)
      out[((size_t)b * S_ + srow) * H_ + h * HD_ + ni * 16 + l15] = (f16)(O[ni][r] * inv);
  }
}

// ---------------- GEMM2: out = attn @ Wo^T (fp32 out) ----------------
__global__ __launch_bounds__(256) void gemm_out(const f16* __restrict__ A,
                                                const f16* __restrict__ W,
                                                float* __restrict__ out) {
  __shared__ __align__(16) f16 As[128 * 32];
  __shared__ __align__(16) f16 Bs[128 * 32];
  const int K = 2048;
  const int m0 = blockIdx.x * 128;
  const int n0 = blockIdx.y * 128;
  const int tid = threadIdx.x;
  const int wave = tid >> 6, lane = tid & 63;
  const int quad = lane >> 4, l15 = lane & 15;
  const int wm = wave >> 1, wn = wave & 1;
  const int G0 = wave * 128 + lane;
  const int r0 = G0 >> 2, c0g = swz(r0, G0 & 3);
  const int r1 = (G0 + 64) >> 2, c1g = swz(r1, (G0 + 64) & 3);

  f32x4 acc[4][4] = {};

  for (int k0 = 0; k0 < K; k0 += 32) {
    async16(A + (size_t)(m0 + r0) * K + k0 + c0g * 8, (const char*)As + (size_t)G0 * 16);
    async16(A + (size_t)(m0 + r1) * K + k0 + c1g * 8, (const char*)As + (size_t)(G0 + 64) * 16);
    async16(W + (size_t)(n0 + r0) * K + k0 + c0g * 8, (const char*)Bs + (size_t)G0 * 16);
    async16(W + (size_t)(n0 + r1) * K + k0 + c1g * 8, (const char*)Bs + (size_t)(G0 + 64) * 16);
    __syncthreads();
    f16x8 a[4], b[4];
#pragma unroll
    for (int mi = 0; mi < 4; ++mi) {
      const int row = wm * 64 + mi * 16 + l15;
      a[mi] = *reinterpret_cast<const f16x8*>(As + row * 32 + swz(row, quad) * 8);
    }
#pragma unroll
    for (int ni = 0; ni < 4; ++ni) {
      const int col = wn * 64 + ni * 16 + l15;
      b[ni] = *reinterpret_cast<const f16x8*>(Bs + col * 32 + swz(col, quad) * 8);
    }
#pragma unroll
    for (int mi = 0; mi < 4; ++mi)
#pragma unroll
      for (int ni = 0; ni < 4; ++ni)
        acc[mi][ni] = __builtin_amdgcn_mfma_f32_16x16x32_f16(a[mi], b[ni], acc[mi][ni], 0, 0, 0);
    __syncthreads();
  }

#pragma unroll
  for (int mi = 0; mi < 4; ++mi) {
#pragma unroll
    for (int ni = 0; ni < 4; ++ni) {
      const int ncol = n0 + wn * 64 + ni * 16 + l15;
#pragma unroll
      for (int r = 0; r < 4; ++r) {
        const int mrow = m0 + wm * 64 + mi * 16 + quad * 4 + r;
        out[(size_t)mrow * 2048 + ncol] = acc[mi][ni][r];
      }
    }
  }
}

extern "C" void kernel_launch(void* const* d_in, const int* in_sizes, int n_in,
                              void* d_out, int out_size, void* d_ws, size_t ws_size,
                              hipStream_t stream) {
  const float* x = (const float*)d_in[0];
  const float* Wq = (const float*)d_in[1];
  const float* Wk = (const float*)d_in[2];
  const float* Wv = (const float*)d_in[3];
  const float* Wo = (const float*)d_in[4];
  float* out = (float*)d_out;
  char* ws = (char*)d_ws;

  f16* x_h  = (f16*)(ws + 0);
  f16* w_h  = (f16*)(ws + 33554432);
  f16* wo_h = (f16*)(ws + 46137344);
  f16* qb   = (f16*)(ws + 54525952);
  f16* kb   = (f16*)(ws + 88080384);
  f16* vtb  = (f16*)(ws + 96468992);
  f16* attn = (f16*)(ws + 104857600);  // needs ws_size >= 138412032

  cast_all<<<26624, 256, 0, stream>>>(x, Wq, Wk, Wv, Wo, x_h, w_h, wo_h);
  gemm_qkv<<<dim3(64, 24), 256, 0, stream>>>(x_h, w_h, qb, kb, vtb);
  attn_kernel<<<dim3(4, 16, 16), 512, 0, stream>>>(qb, kb, vtb, attn);
  gemm_out<<<dim3(64, 16), 256, 0, stream>>>(attn, wo_h, out);
}